// Round 1
// baseline (808.984 us; speedup 1.0000x reference)
//
#include <hip/hip_runtime.h>

// Problem constants (fixed by the reference).
#define Bn    16384
#define Tn    2048
#define HIDn  5
#define NBINS 2048

typedef float v2f __attribute__((ext_vector_type(2)));

static __device__ __forceinline__ float rcp_fast(float v) {
    return __builtin_amdgcn_rcpf(v);
}
static __device__ __forceinline__ float med3(float x, float lo, float hi) {
    return __builtin_amdgcn_fmed3f(x, lo, hi);   // 1-op clamp
}

// Broadcast lane (8g + K) to all lanes of each 8-lane group (ds_swizzle BitMode:
// new_src = (lane & 0x18) | K).
template <int K>
static __device__ __forceinline__ float bcast8(float v) {
    return __int_as_float(
        __builtin_amdgcn_ds_swizzle(__float_as_int(v), (K << 5) | 0x18));
}

// ---------------------------------------------------------------------------
// Pass 0: zero the global histogram bins (ws is poisoned 0xAA by the harness).
// ---------------------------------------------------------------------------
__global__ void zero_kernel(int* __restrict__ gbins) {
    gbins[blockIdx.x * 256 + threadIdx.x] = 0;
}

// ---------------------------------------------------------------------------
// Pass 1: lengths[b] = count of nonzero x[b,t] (exact reference mask.sum
// semantics) + histogram of descending-key d = NBINS - len.
// One wave per row, coalesced float4.
// ---------------------------------------------------------------------------
__global__ __launch_bounds__(256) void len_kernel(const float* __restrict__ x,
                                                  int* __restrict__ lengths,
                                                  int* __restrict__ gbins) {
    const int gtid = blockIdx.x * 256 + threadIdx.x;
    const int row  = gtid >> 6;
    const int lane = threadIdx.x & 63;
    const float4* r = reinterpret_cast<const float4*>(x + (size_t)row * Tn);
    int cnt = 0;
    #pragma unroll
    for (int i = 0; i < Tn / 4 / 64; ++i) {
        float4 v = r[i * 64 + lane];
        cnt += (v.x != 0.0f) + (v.y != 0.0f) + (v.z != 0.0f) + (v.w != 0.0f);
    }
    #pragma unroll
    for (int off = 32; off > 0; off >>= 1) cnt += __shfl_xor(cnt, off, 64);
    if (lane == 0) {
        lengths[row] = cnt;
        const int d = max(0, min(NBINS - 1, NBINS - cnt));
        atomicAdd(&gbins[d], 1);
    }
}

// ---------------------------------------------------------------------------
// Pass 1.5: scan the histogram + scatter -> perm[] sorted by length DESC.
// ---------------------------------------------------------------------------
__global__ __launch_bounds__(1024) void sort_kernel(const int* __restrict__ lengths,
                                                    const int* __restrict__ gbins,
                                                    int* __restrict__ perm) {
    __shared__ int bins[NBINS];
    __shared__ int bsum[1024];
    const int tid = threadIdx.x;
    bins[tid]        = gbins[tid];
    bins[tid + 1024] = gbins[tid + 1024];
    __syncthreads();
    const int a0 = bins[2 * tid], a1 = bins[2 * tid + 1];
    const int s = a0 + a1;
    bsum[tid] = s;
    __syncthreads();
    int acc = s;
    for (int off = 1; off < 1024; off <<= 1) {
        int v = (tid >= off) ? bsum[tid - off] : 0;
        __syncthreads();
        acc += v;
        bsum[tid] = acc;
        __syncthreads();
    }
    const int excl = acc - s;
    bins[2 * tid]     = excl;
    bins[2 * tid + 1] = excl + a0;
    __syncthreads();
    for (int i = tid; i < Bn; i += 1024) {
        int d = NBINS - lengths[i];
        d = max(0, min(NBINS - 1, d));
        const int p = atomicAdd(&bins[d], 1);
        perm[p] = i;
    }
}

// ---------------------------------------------------------------------------
// One LSTM step for one row (lane owns hidden k; gates paired A=(i,f) scaled
// 0.5 for sigma-via-tanh, B=(g,o) scaled (1, 0.5)). Pade(7,6) tanh everywhere,
// clamp +-4 via med3. Cross-mul + sigmoid folds done packed (op_sel swap).
// ---------------------------------------------------------------------------
static __device__ __forceinline__ void lstm_step(
    float xv, bool upd,
    v2f wihA, v2f wihB, v2f bA, v2f bB,
    const v2f* __restrict__ whhA, const v2f* __restrict__ whhB,
    float h0, float h1, float h2, float h3, float h4,
    float& hq, float& c)
{
    // Packed pre-activations (12 pk_fma).
    v2f pA = xv * wihA + bA;
    v2f pB = xv * wihB + bB;
    pA = h0 * whhA[0] + pA;  pB = h0 * whhB[0] + pB;
    pA = h1 * whhA[1] + pA;  pB = h1 * whhB[1] + pB;
    pA = h2 * whhA[2] + pA;  pB = h2 * whhB[2] + pB;
    pA = h3 * whhA[3] + pA;  pB = h3 * whhB[3] + pB;
    pA = h4 * whhA[4] + pA;  pB = h4 * whhB[4] + pB;
    // Pade(7,6) tanh on all four, clamp +-4 (med3).
    v2f tA, tB;
    tA.x = med3(pA.x, -4.0f, 4.0f);  tA.y = med3(pA.y, -4.0f, 4.0f);
    tB.x = med3(pB.x, -4.0f, 4.0f);  tB.y = med3(pB.y, -4.0f, 4.0f);
    const v2f zA = tA * tA, zB = tB * tB;
    const v2f nA = (zA * 21.0f + 1260.0f) * zA + 10395.0f;
    const v2f nB = (zB * 21.0f + 1260.0f) * zB + 10395.0f;
    const v2f dA = ((zA + 210.0f) * zA + 4725.0f) * zA + 10395.0f;
    const v2f dB = ((zB + 210.0f) * zB + 4725.0f) * zB + 10395.0f;
    const float rA = rcp_fast(dA.x * dA.y);
    const float rB = rcp_fast(dB.x * dB.y);
    const v2f pnA = tA * nA, pnB = tB * nB;
    const v2f dAs = {dA.y, dA.x};            // op_sel swap
    const v2f dBs = {dB.y, dB.x};
    const v2f tAv = (pnA * dAs) * rA;        // (tanh(i/2), tanh(f/2))
    const v2f tBv = (pnB * dBs) * rB;        // (tanh(g),   tanh(o/2))
    const v2f sA = tAv * 0.5f + 0.5f;                          // (sig i, sig f)
    const v2f sB = tBv * (v2f){1.0f, 0.5f} + (v2f){0.0f, 0.5f}; // (tanh g, sig o)

    const float cn = fmaf(sA.y, c, sA.x * sB.x);

    // Spine tanh(c), same Pade(7,6).
    const float tc = med3(cn, -4.0f, 4.0f);
    const float zc = tc * tc;
    const float nc = fmaf(zc, fmaf(zc, 21.0f, 1260.0f), 10395.0f);
    const float dc = fmaf(zc, fmaf(zc, zc + 210.0f, 4725.0f), 10395.0f);
    const float hn = (tc * nc) * (sB.y * rcp_fast(dc));

    // Conditional commit (cndmask); frozen past len.
    c  = upd ? cn : c;
    hq = upd ? hn : hq;
}

// ---------------------------------------------------------------------------
// Pass 2: LSTM. TWO rows per 8-lane group (sorted-adjacent ranks 2g, 2g+1 so
// both lengths match), interleaved in registers. 16384 rows / 16 rows-per-wave
// = 1024 waves = exactly 1 wave/SIMD: no co-wave issue contention, and row B's
// independent instruction stream hides row A's ds_swizzle (+~120cy) and
// activation-chain latency (and vice versa). Weights are shared between the
// two rows (same owned hidden index k) -- only ~12 VGPRs of state duplicate.
// ---------------------------------------------------------------------------
__global__ __launch_bounds__(256, 1) void lstm_kernel(const float* __restrict__ x,
                                                      const float* __restrict__ Wih,
                                                      const float* __restrict__ Whh,
                                                      const float* __restrict__ bih,
                                                      const float* __restrict__ bhh,
                                                      const int* __restrict__ lengths,
                                                      const int* __restrict__ perm,
                                                      float* __restrict__ out) {
    const int gtid = blockIdx.x * 256 + threadIdx.x;
    const int grp  = gtid >> 3;              // pair index: rows perm[2g], perm[2g+1]
    const int lsub = threadIdx.x & 7;
    const int k    = min(lsub, 4);           // owned hidden index

    const int ra = perm[2 * grp];
    const int rb = perm[2 * grp + 1];
    const int lenA = lengths[ra];
    const int lenB = lengths[rb];
    const int lenM = max(lenA, lenB);

    // Gate rows: i=k, f=5+k, g=10+k, o=15+k. Pairs A=(i,f) scaled 0.5 (sigma
    // via tanh(x/2)), B=(g,o) scaled (1, 0.5). Shared by both rows.
    v2f wihA, wihB, bA, bB, whhA[HIDn], whhB[HIDn];
    {
        const int gi = k, gf = 5 + k, gg = 10 + k, go = 15 + k;
        wihA = (v2f){ Wih[gi] * 0.5f, Wih[gf] * 0.5f };
        wihB = (v2f){ Wih[gg],        Wih[go] * 0.5f };
        bA   = (v2f){ (bih[gi] + bhh[gi]) * 0.5f, (bih[gf] + bhh[gf]) * 0.5f };
        bB   = (v2f){ (bih[gg] + bhh[gg]),        (bih[go] + bhh[go]) * 0.5f };
        #pragma unroll
        for (int kk = 0; kk < HIDn; ++kk) {
            whhA[kk] = (v2f){ Whh[gi * HIDn + kk] * 0.5f, Whh[gf * HIDn + kk] * 0.5f };
            whhB[kk] = (v2f){ Whh[gg * HIDn + kk],        Whh[go * HIDn + kk] * 0.5f };
        }
    }

    const float* xrA = x + (size_t)ra * Tn;
    const float* xrB = x + (size_t)rb * Tn;

    float hA0 = 0, hA1 = 0, hA2 = 0, hA3 = 0, hA4 = 0, hqA = 0, cA = 0;
    float hB0 = 0, hB1 = 0, hB2 = 0, hB3 = 0, hB4 = 0, hqB = 0, cB = 0;

    float4 xqA = *reinterpret_cast<const float4*>(xrA);
    float4 xqB = *reinterpret_cast<const float4*>(xrB);

    for (int t = 0; __any(t < lenM); t += 4) {
        const int tn = min(t + 4, Tn - 4);
        const float4 xnA = *reinterpret_cast<const float4*>(xrA + tn);
        const float4 xnB = *reinterpret_cast<const float4*>(xrB + tn);
        const float xsA[4] = { xqA.x, xqA.y, xqA.z, xqA.w };
        const float xsB[4] = { xqB.x, xqB.y, xqB.z, xqB.w };
        #pragma unroll
        for (int s = 0; s < 4; ++s) {
            // Row A step, then issue its broadcast; row B's step hides the
            // swizzle latency (and B's swizzles hide under next-step A work).
            lstm_step(xsA[s], (t + s) < lenA, wihA, wihB, bA, bB, whhA, whhB,
                      hA0, hA1, hA2, hA3, hA4, hqA, cA);
            hA0 = bcast8<0>(hqA);
            hA1 = bcast8<1>(hqA);
            hA2 = bcast8<2>(hqA);
            hA3 = bcast8<3>(hqA);
            hA4 = bcast8<4>(hqA);

            lstm_step(xsB[s], (t + s) < lenB, wihA, wihB, bA, bB, whhA, whhB,
                      hB0, hB1, hB2, hB3, hB4, hqB, cB);
            hB0 = bcast8<0>(hqB);
            hB1 = bcast8<1>(hqB);
            hB2 = bcast8<2>(hqB);
            hB3 = bcast8<3>(hqB);
            hB4 = bcast8<4>(hqB);
        }
        xqA = xnA;
        xqB = xnB;
    }

    if (lsub < HIDn) {
        out[(size_t)ra * HIDn + lsub] = hqA;
        out[(size_t)rb * HIDn + lsub] = hqB;
    }
}

extern "C" void kernel_launch(void* const* d_in, const int* in_sizes, int n_in,
                              void* d_out, int out_size, void* d_ws, size_t ws_size,
                              hipStream_t stream) {
    const float* x   = (const float*)d_in[0];  // [B,1,T,1]
    const float* Wih = (const float*)d_in[1];  // [20,1]
    const float* Whh = (const float*)d_in[2];  // [20,5]
    const float* bih = (const float*)d_in[3];  // [20]
    const float* bhh = (const float*)d_in[4];  // [20]
    float* out = (float*)d_out;                // [1,B,5]

    int* lengths = (int*)d_ws;                 // [0, Bn)
    int* perm    = lengths + Bn;               // [Bn, 2Bn)
    int* gbins   = perm + Bn;                  // [2Bn, 2Bn+NBINS)

    zero_kernel<<<NBINS / 256, 256, 0, stream>>>(gbins);
    len_kernel<<<Bn / 4, 256, 0, stream>>>(x, lengths, gbins);
    sort_kernel<<<1, 1024, 0, stream>>>(lengths, gbins, perm);
    lstm_kernel<<<Bn * 8 / 512, 256, 0, stream>>>(x, Wih, Whh, bih, bhh,
                                                  lengths, perm, out);
}

// Round 2
// 703.661 us; speedup vs baseline: 1.1497x; 1.1497x over previous
//
#include <hip/hip_runtime.h>

// Problem constants (fixed by the reference).
#define Bn    16384
#define Tn    2048
#define HIDn  5
#define NBINS 2048

typedef float v2f __attribute__((ext_vector_type(2)));

static __device__ __forceinline__ float rcp_fast(float v) {
    return __builtin_amdgcn_rcpf(v);
}
static __device__ __forceinline__ float med3(float x, float lo, float hi) {
    return __builtin_amdgcn_fmed3f(x, lo, hi);   // 1-op clamp
}

// Broadcast lane K of each 4-lane quad to all lanes of the quad via DPP
// quad_perm:[K,K,K,K]. VALU pipe, ~5-10 cyc dependent latency -- replaces the
// ~120-cyc DS-pipe ds_swizzle that dominated the recurrence chain.
template <int K>
static __device__ __forceinline__ float qbcast(float v) {
    constexpr int ctrl = K | (K << 2) | (K << 4) | (K << 6);
    return __int_as_float(
        __builtin_amdgcn_mov_dpp(__float_as_int(v), ctrl, 0xF, 0xF, true));
}

// ---------------------------------------------------------------------------
// Pass 0: zero the global histogram bins (ws is poisoned 0xAA by the harness).
// ---------------------------------------------------------------------------
__global__ void zero_kernel(int* __restrict__ gbins) {
    gbins[blockIdx.x * 256 + threadIdx.x] = 0;
}

// ---------------------------------------------------------------------------
// Pass 1: lengths[b] = count of nonzero x[b,t] (exact reference mask.sum
// semantics) + histogram of descending-key d = NBINS - len.
// One wave per row, coalesced float4.
// ---------------------------------------------------------------------------
__global__ __launch_bounds__(256) void len_kernel(const float* __restrict__ x,
                                                  int* __restrict__ lengths,
                                                  int* __restrict__ gbins) {
    const int gtid = blockIdx.x * 256 + threadIdx.x;
    const int row  = gtid >> 6;
    const int lane = threadIdx.x & 63;
    const float4* r = reinterpret_cast<const float4*>(x + (size_t)row * Tn);
    int cnt = 0;
    #pragma unroll
    for (int i = 0; i < Tn / 4 / 64; ++i) {
        float4 v = r[i * 64 + lane];
        cnt += (v.x != 0.0f) + (v.y != 0.0f) + (v.z != 0.0f) + (v.w != 0.0f);
    }
    #pragma unroll
    for (int off = 32; off > 0; off >>= 1) cnt += __shfl_xor(cnt, off, 64);
    if (lane == 0) {
        lengths[row] = cnt;
        const int d = max(0, min(NBINS - 1, NBINS - cnt));
        atomicAdd(&gbins[d], 1);
    }
}

// ---------------------------------------------------------------------------
// Pass 1.5: scan the histogram + scatter -> perm[] sorted by length DESC.
// ---------------------------------------------------------------------------
__global__ __launch_bounds__(1024) void sort_kernel(const int* __restrict__ lengths,
                                                    const int* __restrict__ gbins,
                                                    int* __restrict__ perm) {
    __shared__ int bins[NBINS];
    __shared__ int bsum[1024];
    const int tid = threadIdx.x;
    bins[tid]        = gbins[tid];
    bins[tid + 1024] = gbins[tid + 1024];
    __syncthreads();
    const int a0 = bins[2 * tid], a1 = bins[2 * tid + 1];
    const int s = a0 + a1;
    bsum[tid] = s;
    __syncthreads();
    int acc = s;
    for (int off = 1; off < 1024; off <<= 1) {
        int v = (tid >= off) ? bsum[tid - off] : 0;
        __syncthreads();
        acc += v;
        bsum[tid] = acc;
        __syncthreads();
    }
    const int excl = acc - s;
    bins[2 * tid]     = excl;
    bins[2 * tid + 1] = excl + a0;
    __syncthreads();
    for (int i = tid; i < Bn; i += 1024) {
        int d = NBINS - lengths[i];
        d = max(0, min(NBINS - 1, d));
        const int p = atomicAdd(&bins[d], 1);
        perm[p] = i;
    }
}

// ---------------------------------------------------------------------------
// Pass 2: LSTM. 4-lane groups (one row each), lane k owns hidden unit k.
// Hidden unit 4 rides the .y slot of every packed v2f stream (computed
// redundantly by all 4 lanes -- the slot was free), so only h0..h3 need
// cross-lane broadcast, done with DPP quad_perm on the VALU pipe instead of
// ds_swizzle. Chain/step ~160cy; issue/step ~220cy over 16 rows/wave; 1024
// waves = 1 wave/SIMD (issue-bound, no co-wave contention). Numerics are
// bit-identical to the round-0 kernel (same Pade(7,6), same rcp pair-trick,
// same accumulation order).
// ---------------------------------------------------------------------------
__global__ __launch_bounds__(256, 1) void lstm_kernel(const float* __restrict__ x,
                                                      const float* __restrict__ Wih,
                                                      const float* __restrict__ Whh,
                                                      const float* __restrict__ bih,
                                                      const float* __restrict__ bhh,
                                                      const int* __restrict__ lengths,
                                                      const int* __restrict__ perm,
                                                      float* __restrict__ out) {
    const int gtid = blockIdx.x * 256 + threadIdx.x;
    const int grp  = gtid >> 2;          // quad index = sorted rank
    const int k    = threadIdx.x & 3;    // owned hidden unit; all lanes also run unit 4

    const int b   = perm[grp];
    const int len = lengths[b];

    // Gate rows: i=0+u, f=5+u, g=10+u, o=15+u. Streams pack {unit k, unit 4}.
    // I,F,O scaled 0.5 (sigma via tanh(x/2)); G unscaled.
    const int ri0 = k,      ri1 = 4;
    const int rf0 = 5 + k,  rf1 = 9;
    const int rg0 = 10 + k, rg1 = 14;
    const int ro0 = 15 + k, ro1 = 19;

    const v2f wI = { Wih[ri0] * 0.5f, Wih[ri1] * 0.5f };
    const v2f wF = { Wih[rf0] * 0.5f, Wih[rf1] * 0.5f };
    const v2f wG = { Wih[rg0],        Wih[rg1]        };
    const v2f wO = { Wih[ro0] * 0.5f, Wih[ro1] * 0.5f };
    const v2f bI = { (bih[ri0] + bhh[ri0]) * 0.5f, (bih[ri1] + bhh[ri1]) * 0.5f };
    const v2f bF = { (bih[rf0] + bhh[rf0]) * 0.5f, (bih[rf1] + bhh[rf1]) * 0.5f };
    const v2f bG = { (bih[rg0] + bhh[rg0]),        (bih[rg1] + bhh[rg1])        };
    const v2f bO = { (bih[ro0] + bhh[ro0]) * 0.5f, (bih[ro1] + bhh[ro1]) * 0.5f };
    v2f hI[HIDn], hF[HIDn], hG[HIDn], hO[HIDn];
    #pragma unroll
    for (int j = 0; j < HIDn; ++j) {
        hI[j] = (v2f){ Whh[ri0 * HIDn + j] * 0.5f, Whh[ri1 * HIDn + j] * 0.5f };
        hF[j] = (v2f){ Whh[rf0 * HIDn + j] * 0.5f, Whh[rf1 * HIDn + j] * 0.5f };
        hG[j] = (v2f){ Whh[rg0 * HIDn + j],        Whh[rg1 * HIDn + j]        };
        hO[j] = (v2f){ Whh[ro0 * HIDn + j] * 0.5f, Whh[ro1 * HIDn + j] * 0.5f };
    }

    const float* xrow = x + (size_t)b * Tn;
    v2f hq = { 0.0f, 0.0f }, c = { 0.0f, 0.0f };
    float h0 = 0, h1 = 0, h2 = 0, h3 = 0, h4 = 0;

    float4 xq = *reinterpret_cast<const float4*>(xrow);
    for (int t = 0; __any(t < len); t += 4) {
        const float4 xn = *reinterpret_cast<const float4*>(xrow + min(t + 4, Tn - 4));
        const float xs[4] = { xq.x, xq.y, xq.z, xq.w };
        #pragma unroll
        for (int s = 0; s < 4; ++s) {
            const float xv = xs[s];
            // Packed pre-activations: 4 gate streams x 6 pk_fma.
            v2f pI = xv * wI + bI;
            v2f pF = xv * wF + bF;
            v2f pG = xv * wG + bG;
            v2f pO = xv * wO + bO;
            pI = h0 * hI[0] + pI; pF = h0 * hF[0] + pF; pG = h0 * hG[0] + pG; pO = h0 * hO[0] + pO;
            pI = h1 * hI[1] + pI; pF = h1 * hF[1] + pF; pG = h1 * hG[1] + pG; pO = h1 * hO[1] + pO;
            pI = h2 * hI[2] + pI; pF = h2 * hF[2] + pF; pG = h2 * hG[2] + pG; pO = h2 * hO[2] + pO;
            pI = h3 * hI[3] + pI; pF = h3 * hF[3] + pF; pG = h3 * hG[3] + pG; pO = h3 * hO[3] + pO;
            pI = h4 * hI[4] + pI; pF = h4 * hF[4] + pF; pG = h4 * hG[4] + pG; pO = h4 * hO[4] + pO;
            // Pade(7,6) tanh on all 8 values, clamp +-4 (med3).
            v2f tI, tF, tG, tO;
            tI.x = med3(pI.x, -4.0f, 4.0f);  tI.y = med3(pI.y, -4.0f, 4.0f);
            tF.x = med3(pF.x, -4.0f, 4.0f);  tF.y = med3(pF.y, -4.0f, 4.0f);
            tG.x = med3(pG.x, -4.0f, 4.0f);  tG.y = med3(pG.y, -4.0f, 4.0f);
            tO.x = med3(pO.x, -4.0f, 4.0f);  tO.y = med3(pO.y, -4.0f, 4.0f);
            const v2f zI = tI * tI, zF = tF * tF, zG = tG * tG, zO = tO * tO;
            const v2f nI = (zI * 21.0f + 1260.0f) * zI + 10395.0f;
            const v2f nF = (zF * 21.0f + 1260.0f) * zF + 10395.0f;
            const v2f nG = (zG * 21.0f + 1260.0f) * zG + 10395.0f;
            const v2f nO = (zO * 21.0f + 1260.0f) * zO + 10395.0f;
            const v2f dI = ((zI + 210.0f) * zI + 4725.0f) * zI + 10395.0f;
            const v2f dF = ((zF + 210.0f) * zF + 4725.0f) * zF + 10395.0f;
            const v2f dG = ((zG + 210.0f) * zG + 4725.0f) * zG + 10395.0f;
            const v2f dO = ((zO + 210.0f) * zO + 4725.0f) * zO + 10395.0f;
            // rcp pair-trick: one reciprocal per (i,f) and (g,o) pair per unit.
            const v2f prIF = dI * dF;
            const v2f prGO = dG * dO;
            const v2f rIF = { rcp_fast(prIF.x), rcp_fast(prIF.y) };
            const v2f rGO = { rcp_fast(prGO.x), rcp_fast(prGO.y) };
            const v2f thI = ((tI * nI) * dF) * rIF;
            const v2f thF = ((tF * nF) * dI) * rIF;
            const v2f thG = ((tG * nG) * dO) * rGO;
            const v2f thO = ((tO * nO) * dG) * rGO;
            const v2f sI = thI * 0.5f + 0.5f;   // sigmoid(i)
            const v2f sF = thF * 0.5f + 0.5f;   // sigmoid(f)
            const v2f sO = thO * 0.5f + 0.5f;   // sigmoid(o)

            const v2f cn = sF * c + sI * thG;

            // Spine tanh(c), same Pade(7,6).
            v2f tc;
            tc.x = med3(cn.x, -4.0f, 4.0f);  tc.y = med3(cn.y, -4.0f, 4.0f);
            const v2f zc = tc * tc;
            const v2f nc = (zc * 21.0f + 1260.0f) * zc + 10395.0f;
            const v2f dc = ((zc + 210.0f) * zc + 4725.0f) * zc + 10395.0f;
            const v2f rc = { rcp_fast(dc.x), rcp_fast(dc.y) };
            const v2f hn = (tc * nc) * (sO * rc);

            // Conditional commit (cndmask); frozen past len.
            const bool upd = (t + s) < len;
            c.x  = upd ? cn.x : c.x;    c.y  = upd ? cn.y : c.y;
            hq.x = upd ? hn.x : hq.x;   hq.y = upd ? hn.y : hq.y;

            // VALU-pipe broadcast of h0..h3; h4 is lane-local (.y slot).
            h0 = qbcast<0>(hq.x);
            h1 = qbcast<1>(hq.x);
            h2 = qbcast<2>(hq.x);
            h3 = qbcast<3>(hq.x);
            h4 = hq.y;
        }
        xq = xn;
    }

    out[(size_t)b * HIDn + k] = hq.x;
    if (k == 3) out[(size_t)b * HIDn + 4] = hq.y;
}

extern "C" void kernel_launch(void* const* d_in, const int* in_sizes, int n_in,
                              void* d_out, int out_size, void* d_ws, size_t ws_size,
                              hipStream_t stream) {
    const float* x   = (const float*)d_in[0];  // [B,1,T,1]
    const float* Wih = (const float*)d_in[1];  // [20,1]
    const float* Whh = (const float*)d_in[2];  // [20,5]
    const float* bih = (const float*)d_in[3];  // [20]
    const float* bhh = (const float*)d_in[4];  // [20]
    float* out = (float*)d_out;                // [1,B,5]

    int* lengths = (int*)d_ws;                 // [0, Bn)
    int* perm    = lengths + Bn;               // [Bn, 2Bn)
    int* gbins   = perm + Bn;                  // [2Bn, 2Bn+NBINS)

    zero_kernel<<<NBINS / 256, 256, 0, stream>>>(gbins);
    len_kernel<<<Bn / 4, 256, 0, stream>>>(x, lengths, gbins);
    sort_kernel<<<1, 1024, 0, stream>>>(lengths, gbins, perm);
    lstm_kernel<<<Bn * 4 / 256, 256, 0, stream>>>(x, Wih, Whh, bih, bhh,
                                                  lengths, perm, out);
}

// Round 3
// 619.520 us; speedup vs baseline: 1.3058x; 1.1358x over previous
//
#include <hip/hip_runtime.h>

// Problem constants (fixed by the reference).
#define Bn    16384
#define Tn    2048
#define HIDn  5
#define NBINS 2048

typedef float v2f __attribute__((ext_vector_type(2)));

static __device__ __forceinline__ float rcp_fast(float v) {
    return __builtin_amdgcn_rcpf(v);
}
static __device__ __forceinline__ float med3(float x, float lo, float hi) {
    return __builtin_amdgcn_fmed3f(x, lo, hi);   // 1-op clamp
}

// ---------------------------------------------------------------------------
// Broadcast lane (8g + K) to all 8 lanes of its group using two DPP hops on
// the VALU pipe (replaces ds_swizzle: no DS latency, no lgkmcnt, no DS-pipe
// queueing across the CU's waves).
//   hop 1: quad_perm[K,K,K,K]  -> each quad holds its own lane-K value; the
//          source quad (q_even for K<4, q_odd for K=4) now has the true h_K.
//   hop 2: row_shr:4 (K<4) or row_shl:4 (K=4) with bank_mask merging the
//          shifted value ONLY into the quads that had junk.
// ---------------------------------------------------------------------------
template <int K>
static __device__ __forceinline__ float bcast8_dpp(float v) {
    const int iv = __float_as_int(v);
    if constexpr (K < 4) {
        constexpr int qp = K | (K << 2) | (K << 4) | (K << 6);
        const int t = __builtin_amdgcn_mov_dpp(iv, qp, 0xF, 0xF, false);
        // row_shr:4 = 0x114; update odd banks (q1,q3) from even banks.
        const int r = __builtin_amdgcn_update_dpp(t, t, 0x114, 0xF, 0xA, false);
        return __int_as_float(r);
    } else {
        // h4 lives at lane 8g+4 (lane 0 of the odd quad).
        const int t = __builtin_amdgcn_mov_dpp(iv, 0x00, 0xF, 0xF, false);
        // row_shl:4 = 0x104; update even banks (q0,q2) from odd banks.
        const int r = __builtin_amdgcn_update_dpp(t, t, 0x104, 0xF, 0x5, false);
        return __int_as_float(r);
    }
}

// ---------------------------------------------------------------------------
// Pass 0: zero the global histogram bins (ws is poisoned 0xAA by the harness).
// ---------------------------------------------------------------------------
__global__ void zero_kernel(int* __restrict__ gbins) {
    gbins[blockIdx.x * 256 + threadIdx.x] = 0;
}

// ---------------------------------------------------------------------------
// Pass 1: lengths[b] = count of nonzero x[b,t] (exact reference mask.sum
// semantics) + histogram of descending-key d = NBINS - len.
// One wave per row, coalesced float4.
// ---------------------------------------------------------------------------
__global__ __launch_bounds__(256) void len_kernel(const float* __restrict__ x,
                                                  int* __restrict__ lengths,
                                                  int* __restrict__ gbins) {
    const int gtid = blockIdx.x * 256 + threadIdx.x;
    const int row  = gtid >> 6;
    const int lane = threadIdx.x & 63;
    const float4* r = reinterpret_cast<const float4*>(x + (size_t)row * Tn);
    int cnt = 0;
    #pragma unroll
    for (int i = 0; i < Tn / 4 / 64; ++i) {
        float4 v = r[i * 64 + lane];
        cnt += (v.x != 0.0f) + (v.y != 0.0f) + (v.z != 0.0f) + (v.w != 0.0f);
    }
    #pragma unroll
    for (int off = 32; off > 0; off >>= 1) cnt += __shfl_xor(cnt, off, 64);
    if (lane == 0) {
        lengths[row] = cnt;
        const int d = max(0, min(NBINS - 1, NBINS - cnt));
        atomicAdd(&gbins[d], 1);
    }
}

// ---------------------------------------------------------------------------
// Pass 1.5: scan the histogram + scatter -> perm[] sorted by length DESC.
// ---------------------------------------------------------------------------
__global__ __launch_bounds__(1024) void sort_kernel(const int* __restrict__ lengths,
                                                    const int* __restrict__ gbins,
                                                    int* __restrict__ perm) {
    __shared__ int bins[NBINS];
    __shared__ int bsum[1024];
    const int tid = threadIdx.x;
    bins[tid]        = gbins[tid];
    bins[tid + 1024] = gbins[tid + 1024];
    __syncthreads();
    const int a0 = bins[2 * tid], a1 = bins[2 * tid + 1];
    const int s = a0 + a1;
    bsum[tid] = s;
    __syncthreads();
    int acc = s;
    for (int off = 1; off < 1024; off <<= 1) {
        int v = (tid >= off) ? bsum[tid - off] : 0;
        __syncthreads();
        acc += v;
        bsum[tid] = acc;
        __syncthreads();
    }
    const int excl = acc - s;
    bins[2 * tid]     = excl;
    bins[2 * tid + 1] = excl + a0;
    __syncthreads();
    for (int i = tid; i < Bn; i += 1024) {
        int d = NBINS - lengths[i];
        d = max(0, min(NBINS - 1, d));
        const int p = atomicAdd(&bins[d], 1);
        perm[p] = i;
    }
}

// ---------------------------------------------------------------------------
// Pass 2: LSTM. Round-0 structure (8 lanes/group, one row each, lane
// k=min(lsub,4) owns hidden k; 8 rows/wave, 2048 waves = 2 waves/SIMD TLP)
// with the two measured latency sources removed:
//   - h-broadcast on the VALU pipe (2-hop DPP) instead of ds_swizzle
//     (-~130cy DS latency, no lgkmcnt, no DS-pipe queueing per CU)
//   - 2-deep x prefetch queue: load for t+8 issued at iteration top, so
//     HBM latency (~900cy cold) can never reach the recurrence chain.
// Math identical to the verified round-0 kernel (packed (i,f)/(g,o) streams,
// Pade(7,6) tanh, pair-rcp, sigma folded as 0.5+0.5*tanh(x/2)).
// ---------------------------------------------------------------------------
__global__ __launch_bounds__(256, 2) void lstm_kernel(const float* __restrict__ x,
                                                      const float* __restrict__ Wih,
                                                      const float* __restrict__ Whh,
                                                      const float* __restrict__ bih,
                                                      const float* __restrict__ bhh,
                                                      const int* __restrict__ lengths,
                                                      const int* __restrict__ perm,
                                                      float* __restrict__ out) {
    const int gtid = blockIdx.x * 256 + threadIdx.x;
    const int grp  = gtid >> 3;              // group-of-8 index = sorted rank
    const int lsub = threadIdx.x & 7;
    const int k    = min(lsub, 4);           // owned hidden index

    const int b   = perm[grp];
    const int len = lengths[b];

    // Gate rows: i=k, f=5+k, g=10+k, o=15+k. Pairs A=(i,f) scaled 0.5 (sigma
    // via tanh(x/2)), B=(g,o) scaled (1, 0.5).
    v2f wihA, wihB, bA, bB, whhA[HIDn], whhB[HIDn];
    {
        const int gi = k, gf = 5 + k, gg = 10 + k, go = 15 + k;
        wihA = (v2f){ Wih[gi] * 0.5f, Wih[gf] * 0.5f };
        wihB = (v2f){ Wih[gg],        Wih[go] * 0.5f };
        bA   = (v2f){ (bih[gi] + bhh[gi]) * 0.5f, (bih[gf] + bhh[gf]) * 0.5f };
        bB   = (v2f){ (bih[gg] + bhh[gg]),        (bih[go] + bhh[go]) * 0.5f };
        #pragma unroll
        for (int kk = 0; kk < HIDn; ++kk) {
            whhA[kk] = (v2f){ Whh[gi * HIDn + kk] * 0.5f, Whh[gf * HIDn + kk] * 0.5f };
            whhB[kk] = (v2f){ Whh[gg * HIDn + kk],        Whh[go * HIDn + kk] * 0.5f };
        }
    }

    const float* xrow = x + (size_t)b * Tn;
    float h0 = 0, h1 = 0, h2 = 0, h3 = 0, h4 = 0;
    float hq = 0, c = 0;

    // 2-deep prefetch queue: xq = steps t..t+3, xp = t+4..t+7.
    float4 xq = *reinterpret_cast<const float4*>(xrow);
    float4 xp = *reinterpret_cast<const float4*>(xrow + 4);
    for (int t = 0; __any(t < len); t += 4) {
        const float4 xf = *reinterpret_cast<const float4*>(xrow + min(t + 8, Tn - 4));
        const float xs[4] = { xq.x, xq.y, xq.z, xq.w };
        #pragma unroll
        for (int s = 0; s < 4; ++s) {
            const float xv = xs[s];
            // Packed pre-activations (6 pk_fma per pair).
            v2f pA = xv * wihA + bA;
            v2f pB = xv * wihB + bB;
            pA = h0 * whhA[0] + pA;  pB = h0 * whhB[0] + pB;
            pA = h1 * whhA[1] + pA;  pB = h1 * whhB[1] + pB;
            pA = h2 * whhA[2] + pA;  pB = h2 * whhB[2] + pB;
            pA = h3 * whhA[3] + pA;  pB = h3 * whhB[3] + pB;
            pA = h4 * whhA[4] + pA;  pB = h4 * whhB[4] + pB;
            // Pade(7,6) tanh on all four, clamp +-4 (med3).
            v2f tA, tB;
            tA.x = med3(pA.x, -4.0f, 4.0f);  tA.y = med3(pA.y, -4.0f, 4.0f);
            tB.x = med3(pB.x, -4.0f, 4.0f);  tB.y = med3(pB.y, -4.0f, 4.0f);
            const v2f zA = tA * tA, zB = tB * tB;
            const v2f nA = (zA * 21.0f + 1260.0f) * zA + 10395.0f;
            const v2f nB = (zB * 21.0f + 1260.0f) * zB + 10395.0f;
            const v2f dA = ((zA + 210.0f) * zA + 4725.0f) * zA + 10395.0f;
            const v2f dB = ((zB + 210.0f) * zB + 4725.0f) * zB + 10395.0f;
            const float rA = rcp_fast(dA.x * dA.y);
            const float rB = rcp_fast(dB.x * dB.y);
            const v2f pnA = tA * nA, pnB = tB * nB;
            const float ti = (pnA.x * dA.y) * rA;
            const float tf = (pnA.y * dA.x) * rA;
            const float tg = (pnB.x * dB.y) * rB;
            const float to = (pnB.y * dB.x) * rB;
            const float gi_ = fmaf(ti, 0.5f, 0.5f);   // sigmoid(i)
            const float gf_ = fmaf(tf, 0.5f, 0.5f);   // sigmoid(f)
            const float oo  = fmaf(to, 0.5f, 0.5f);   // sigmoid(o)

            const float cn = fmaf(gf_, c, gi_ * tg);

            // Spine tanh(c), same Pade(7,6).
            const float tc = med3(cn, -4.0f, 4.0f);
            const float zc = tc * tc;
            const float nc = fmaf(zc, fmaf(zc, 21.0f, 1260.0f), 10395.0f);
            const float dc = fmaf(zc, fmaf(zc, zc + 210.0f, 4725.0f), 10395.0f);
            const float hn = (tc * nc) * (oo * rcp_fast(dc));

            // Conditional commit (cndmask); frozen past len.
            const bool upd = (t + s) < len;
            c  = upd ? cn : c;
            hq = upd ? hn : hq;

            // VALU-pipe broadcast (2 DPP hops each), no DS.
            h0 = bcast8_dpp<0>(hq);
            h1 = bcast8_dpp<1>(hq);
            h2 = bcast8_dpp<2>(hq);
            h3 = bcast8_dpp<3>(hq);
            h4 = bcast8_dpp<4>(hq);
        }
        xq = xp;
        xp = xf;
    }

    if (lsub < HIDn) out[(size_t)b * HIDn + lsub] = hq;
}

extern "C" void kernel_launch(void* const* d_in, const int* in_sizes, int n_in,
                              void* d_out, int out_size, void* d_ws, size_t ws_size,
                              hipStream_t stream) {
    const float* x   = (const float*)d_in[0];  // [B,1,T,1]
    const float* Wih = (const float*)d_in[1];  // [20,1]
    const float* Whh = (const float*)d_in[2];  // [20,5]
    const float* bih = (const float*)d_in[3];  // [20]
    const float* bhh = (const float*)d_in[4];  // [20]
    float* out = (float*)d_out;                // [1,B,5]

    int* lengths = (int*)d_ws;                 // [0, Bn)
    int* perm    = lengths + Bn;               // [Bn, 2Bn)
    int* gbins   = perm + Bn;                  // [2Bn, 2Bn+NBINS)

    zero_kernel<<<NBINS / 256, 256, 0, stream>>>(gbins);
    len_kernel<<<Bn / 4, 256, 0, stream>>>(x, lengths, gbins);
    sort_kernel<<<1, 1024, 0, stream>>>(lengths, gbins, perm);
    lstm_kernel<<<Bn * 8 / 256, 256, 0, stream>>>(x, Wih, Whh, bih, bhh,
                                                  lengths, perm, out);
}

// Round 4
// 588.567 us; speedup vs baseline: 1.3745x; 1.0526x over previous
//
#include <hip/hip_runtime.h>

// Problem constants (fixed by the reference).
#define Bn    16384
#define Tn    2048
#define HIDn  5
#define NBINS 2048

typedef float v2f __attribute__((ext_vector_type(2)));

static __device__ __forceinline__ float rcp_fast(float v) {
    return __builtin_amdgcn_rcpf(v);
}
static __device__ __forceinline__ float med3(float x, float lo, float hi) {
    return __builtin_amdgcn_fmed3f(x, lo, hi);   // 1-op clamp
}

// Broadcast lane (8g + K) to all lanes of each 8-lane group (ds_swizzle BitMode:
// new_src = (lane & 0x18) | K).
template <int K>
static __device__ __forceinline__ float bcast8(float v) {
    return __int_as_float(
        __builtin_amdgcn_ds_swizzle(__float_as_int(v), (K << 5) | 0x18));
}

// ---------------------------------------------------------------------------
// Pass 0: zero the global histogram bins (ws is poisoned 0xAA by the harness).
// ---------------------------------------------------------------------------
__global__ void zero_kernel(int* __restrict__ gbins) {
    gbins[blockIdx.x * 256 + threadIdx.x] = 0;
}

// ---------------------------------------------------------------------------
// Pass 1: lengths[b] = count of nonzero x[b,t] (exact reference mask.sum
// semantics) + histogram of descending-key d = NBINS - len.
// One wave per row, coalesced float4.
// ---------------------------------------------------------------------------
__global__ __launch_bounds__(256) void len_kernel(const float* __restrict__ x,
                                                  int* __restrict__ lengths,
                                                  int* __restrict__ gbins) {
    const int gtid = blockIdx.x * 256 + threadIdx.x;
    const int row  = gtid >> 6;
    const int lane = threadIdx.x & 63;
    const float4* r = reinterpret_cast<const float4*>(x + (size_t)row * Tn);
    int cnt = 0;
    #pragma unroll
    for (int i = 0; i < Tn / 4 / 64; ++i) {
        float4 v = r[i * 64 + lane];
        cnt += (v.x != 0.0f) + (v.y != 0.0f) + (v.z != 0.0f) + (v.w != 0.0f);
    }
    #pragma unroll
    for (int off = 32; off > 0; off >>= 1) cnt += __shfl_xor(cnt, off, 64);
    if (lane == 0) {
        lengths[row] = cnt;
        const int d = max(0, min(NBINS - 1, NBINS - cnt));
        atomicAdd(&gbins[d], 1);
    }
}

// ---------------------------------------------------------------------------
// Pass 1.5: scan the histogram + scatter -> perm[] sorted by length DESC.
// ---------------------------------------------------------------------------
__global__ __launch_bounds__(1024) void sort_kernel(const int* __restrict__ lengths,
                                                    const int* __restrict__ gbins,
                                                    int* __restrict__ perm) {
    __shared__ int bins[NBINS];
    __shared__ int bsum[1024];
    const int tid = threadIdx.x;
    bins[tid]        = gbins[tid];
    bins[tid + 1024] = gbins[tid + 1024];
    __syncthreads();
    const int a0 = bins[2 * tid], a1 = bins[2 * tid + 1];
    const int s = a0 + a1;
    bsum[tid] = s;
    __syncthreads();
    int acc = s;
    for (int off = 1; off < 1024; off <<= 1) {
        int v = (tid >= off) ? bsum[tid - off] : 0;
        __syncthreads();
        acc += v;
        bsum[tid] = acc;
        __syncthreads();
    }
    const int excl = acc - s;
    bins[2 * tid]     = excl;
    bins[2 * tid + 1] = excl + a0;
    __syncthreads();
    for (int i = tid; i < Bn; i += 1024) {
        int d = NBINS - lengths[i];
        d = max(0, min(NBINS - 1, d));
        const int p = atomicAdd(&bins[d], 1);
        perm[p] = i;
    }
}

// ---------------------------------------------------------------------------
// Pass 2: LSTM. Round-0 structure (8 lanes/group, lane k=min(lsub,4) owns
// hidden k, ds_swizzle broadcast, 2 waves/SIMD) with the dependency chain
// surgically shortened (model: window = chain; co-wave issue rides free):
//   - h-ladder as a depth-4 tree instead of 6 serial pk_fma        (-16 cy)
//   - 4 independent v_rcp instead of the pair-trick (pre-mul and a
//     cross-mul were on the chain; issue has ~100cy headroom)      (-16 cy)
//   - cn = 0.5*c*(1+tf) + 0.5*tg*(1+ti): 2 deps after tf, not 3    (-8 cy)
//   - hn = ((tc*nc)*oo)*rc: triple product overlaps the rcp        (-8 cy)
// Numerics algebraically identical to round 0 (Pade(7,6), clamp +-4).
// ---------------------------------------------------------------------------
__global__ __launch_bounds__(256, 2) void lstm_kernel(const float* __restrict__ x,
                                                      const float* __restrict__ Wih,
                                                      const float* __restrict__ Whh,
                                                      const float* __restrict__ bih,
                                                      const float* __restrict__ bhh,
                                                      const int* __restrict__ lengths,
                                                      const int* __restrict__ perm,
                                                      float* __restrict__ out) {
    const int gtid = blockIdx.x * 256 + threadIdx.x;
    const int grp  = gtid >> 3;              // group-of-8 index = sorted rank
    const int lsub = threadIdx.x & 7;
    const int k    = min(lsub, 4);           // owned hidden index

    const int b   = perm[grp];
    const int len = lengths[b];

    // Gate rows: i=k, f=5+k, g=10+k, o=15+k. Pairs A=(i,f) scaled 0.5 (sigma
    // via tanh(x/2)), B=(g,o) scaled (1, 0.5).
    v2f wihA, wihB, bA, bB, whhA[HIDn], whhB[HIDn];
    {
        const int gi = k, gf = 5 + k, gg = 10 + k, go = 15 + k;
        wihA = (v2f){ Wih[gi] * 0.5f, Wih[gf] * 0.5f };
        wihB = (v2f){ Wih[gg],        Wih[go] * 0.5f };
        bA   = (v2f){ (bih[gi] + bhh[gi]) * 0.5f, (bih[gf] + bhh[gf]) * 0.5f };
        bB   = (v2f){ (bih[gg] + bhh[gg]),        (bih[go] + bhh[go]) * 0.5f };
        #pragma unroll
        for (int kk = 0; kk < HIDn; ++kk) {
            whhA[kk] = (v2f){ Whh[gi * HIDn + kk] * 0.5f, Whh[gf * HIDn + kk] * 0.5f };
            whhB[kk] = (v2f){ Whh[gg * HIDn + kk],        Whh[go * HIDn + kk] * 0.5f };
        }
    }

    const float* xrow = x + (size_t)b * Tn;
    float h0 = 0, h1 = 0, h2 = 0, h3 = 0, h4 = 0;
    float hq = 0, c = 0;

    float4 xq = *reinterpret_cast<const float4*>(xrow);
    for (int t = 0; __any(t < len); t += 4) {
        const float4 xn = *reinterpret_cast<const float4*>(xrow + min(t + 4, Tn - 4));
        const float xs[4] = { xq.x, xq.y, xq.z, xq.w };
        #pragma unroll
        for (int s = 0; s < 4; ++s) {
            const float xv = xs[s];
            // x-part (off-chain) then depth-4 tree ladder over h0..h4.
            const v2f xA = xv * wihA + bA;
            const v2f xB = xv * wihB + bB;
            const v2f tA0 = h0 * whhA[0] + xA;
            const v2f tB0 = h0 * whhB[0] + xB;
            const v2f mA2 = h2 * whhA[2];
            const v2f mB2 = h2 * whhB[2];
            const v2f tA1 = h1 * whhA[1] + mA2;
            const v2f tB1 = h1 * whhB[1] + mB2;
            const v2f mA4 = h4 * whhA[4];
            const v2f mB4 = h4 * whhB[4];
            const v2f tA2 = h3 * whhA[3] + mA4;
            const v2f tB2 = h3 * whhB[3] + mB4;
            const v2f pA = (tA0 + tA1) + tA2;
            const v2f pB = (tB0 + tB1) + tB2;
            // Pade(7,6) tanh on all four, clamp +-4 (med3).
            v2f tA, tB;
            tA.x = med3(pA.x, -4.0f, 4.0f);  tA.y = med3(pA.y, -4.0f, 4.0f);
            tB.x = med3(pB.x, -4.0f, 4.0f);  tB.y = med3(pB.y, -4.0f, 4.0f);
            const v2f zA = tA * tA, zB = tB * tB;
            const v2f nA = (zA * 21.0f + 1260.0f) * zA + 10395.0f;
            const v2f nB = (zB * 21.0f + 1260.0f) * zB + 10395.0f;
            const v2f dA = ((zA + 210.0f) * zA + 4725.0f) * zA + 10395.0f;
            const v2f dB = ((zB + 210.0f) * zB + 4725.0f) * zB + 10395.0f;
            // 4 independent reciprocals (latency-optimal; pn* overlap them).
            const float rIx = rcp_fast(dA.x);
            const float rIy = rcp_fast(dA.y);
            const float rGx = rcp_fast(dB.x);
            const float rGy = rcp_fast(dB.y);
            const v2f pnA = tA * nA, pnB = tB * nB;
            const float ti = pnA.x * rIx;   // tanh(i/2)
            const float tf = pnA.y * rIy;   // tanh(f/2)
            const float tg = pnB.x * rGx;   // tanh(g)
            const float to = pnB.y * rGy;   // tanh(o/2)

            // cn = sigmoid(f)*c + sigmoid(i)*g, refactored to depth 2:
            //    = 0.5*c*(1+tf) + 0.5*tg*(1+ti)
            const float qf = fmaf(tf, c, c);      // c*(1+tf)
            const float qi = fmaf(ti, tg, tg);    // tg*(1+ti)
            const float cn = fmaf(qf, 0.5f, 0.5f * qi);
            const float oo = fmaf(to, 0.5f, 0.5f);   // sigmoid(o)

            // Spine tanh(c), same Pade(7,6); triple product overlaps rcp.
            const float tc = med3(cn, -4.0f, 4.0f);
            const float zc = tc * tc;
            const float nc = fmaf(zc, fmaf(zc, 21.0f, 1260.0f), 10395.0f);
            const float dc = fmaf(zc, fmaf(zc, zc + 210.0f, 4725.0f), 10395.0f);
            const float rc  = rcp_fast(dc);
            const float pre = (tc * nc) * oo;
            const float hn  = pre * rc;

            // Conditional commit (cndmask); frozen past len.
            const bool upd = (t + s) < len;
            c  = upd ? cn : c;
            hq = upd ? hn : hq;

            h0 = bcast8<0>(hq);
            h1 = bcast8<1>(hq);
            h2 = bcast8<2>(hq);
            h3 = bcast8<3>(hq);
            h4 = bcast8<4>(hq);
        }
        xq = xn;
    }

    if (lsub < HIDn) out[(size_t)b * HIDn + lsub] = hq;
}

extern "C" void kernel_launch(void* const* d_in, const int* in_sizes, int n_in,
                              void* d_out, int out_size, void* d_ws, size_t ws_size,
                              hipStream_t stream) {
    const float* x   = (const float*)d_in[0];  // [B,1,T,1]
    const float* Wih = (const float*)d_in[1];  // [20,1]
    const float* Whh = (const float*)d_in[2];  // [20,5]
    const float* bih = (const float*)d_in[3];  // [20]
    const float* bhh = (const float*)d_in[4];  // [20]
    float* out = (float*)d_out;                // [1,B,5]

    int* lengths = (int*)d_ws;                 // [0, Bn)
    int* perm    = lengths + Bn;               // [Bn, 2Bn)
    int* gbins   = perm + Bn;                  // [2Bn, 2Bn+NBINS)

    zero_kernel<<<NBINS / 256, 256, 0, stream>>>(gbins);
    len_kernel<<<Bn / 4, 256, 0, stream>>>(x, lengths, gbins);
    sort_kernel<<<1, 1024, 0, stream>>>(lengths, gbins, perm);
    lstm_kernel<<<Bn * 8 / 256, 256, 0, stream>>>(x, Wih, Whh, bih, bhh,
                                                  lengths, perm, out);
}

// Round 5
// 577.812 us; speedup vs baseline: 1.4001x; 1.0186x over previous
//
#include <hip/hip_runtime.h>

// Problem constants (fixed by the reference).
#define Bn    16384
#define Tn    2048
#define HIDn  5
#define NBINS 2048

typedef float v2f __attribute__((ext_vector_type(2)));

static __device__ __forceinline__ float rcp_fast(float v) {
    return __builtin_amdgcn_rcpf(v);
}
static __device__ __forceinline__ float exp2_fast(float v) {
    return __builtin_amdgcn_exp2f(v);    // v_exp_f32, D = 2^S0
}

// Broadcast lane (8g + K) to all lanes of each 8-lane group (ds_swizzle BitMode:
// new_src = (lane & 0x18) | K).
template <int K>
static __device__ __forceinline__ float bcast8(float v) {
    return __int_as_float(
        __builtin_amdgcn_ds_swizzle(__float_as_int(v), (K << 5) | 0x18));
}

// ---------------------------------------------------------------------------
// Pass 0: zero the global histogram bins (ws is poisoned 0xAA by the harness).
// ---------------------------------------------------------------------------
__global__ void zero_kernel(int* __restrict__ gbins) {
    gbins[blockIdx.x * 256 + threadIdx.x] = 0;
}

// ---------------------------------------------------------------------------
// Pass 1: lengths[b] = count of nonzero x[b,t] (exact reference mask.sum
// semantics) + histogram of descending-key d = NBINS - len.
// One wave per row, coalesced float4.
// ---------------------------------------------------------------------------
__global__ __launch_bounds__(256) void len_kernel(const float* __restrict__ x,
                                                  int* __restrict__ lengths,
                                                  int* __restrict__ gbins) {
    const int gtid = blockIdx.x * 256 + threadIdx.x;
    const int row  = gtid >> 6;
    const int lane = threadIdx.x & 63;
    const float4* r = reinterpret_cast<const float4*>(x + (size_t)row * Tn);
    int cnt = 0;
    #pragma unroll
    for (int i = 0; i < Tn / 4 / 64; ++i) {
        float4 v = r[i * 64 + lane];
        cnt += (v.x != 0.0f) + (v.y != 0.0f) + (v.z != 0.0f) + (v.w != 0.0f);
    }
    #pragma unroll
    for (int off = 32; off > 0; off >>= 1) cnt += __shfl_xor(cnt, off, 64);
    if (lane == 0) {
        lengths[row] = cnt;
        const int d = max(0, min(NBINS - 1, NBINS - cnt));
        atomicAdd(&gbins[d], 1);
    }
}

// ---------------------------------------------------------------------------
// Pass 1.5: scan the histogram + scatter -> perm[] sorted by length DESC.
// ---------------------------------------------------------------------------
__global__ __launch_bounds__(1024) void sort_kernel(const int* __restrict__ lengths,
                                                    const int* __restrict__ gbins,
                                                    int* __restrict__ perm) {
    __shared__ int bins[NBINS];
    __shared__ int bsum[1024];
    const int tid = threadIdx.x;
    bins[tid]        = gbins[tid];
    bins[tid + 1024] = gbins[tid + 1024];
    __syncthreads();
    const int a0 = bins[2 * tid], a1 = bins[2 * tid + 1];
    const int s = a0 + a1;
    bsum[tid] = s;
    __syncthreads();
    int acc = s;
    for (int off = 1; off < 1024; off <<= 1) {
        int v = (tid >= off) ? bsum[tid - off] : 0;
        __syncthreads();
        acc += v;
        bsum[tid] = acc;
        __syncthreads();
    }
    const int excl = acc - s;
    bins[2 * tid]     = excl;
    bins[2 * tid + 1] = excl + a0;
    __syncthreads();
    for (int i = tid; i < Bn; i += 1024) {
        int d = NBINS - lengths[i];
        d = max(0, min(NBINS - 1, d));
        const int p = atomicAdd(&bins[d], 1);
        perm[p] = i;
    }
}

// ---------------------------------------------------------------------------
// Pass 2: LSTM. Round-0 structure (8 lanes/group, lane k=min(lsub,4) owns
// hidden k, ds_swizzle broadcast, 2 waves/SIMD). Measured model at W=2:
// window = co-wave issue + ~200cy lockstep residue. Two levers:
//  (1) ISSUE: activations via hardware exp2 instead of Pade(7,6):
//      sigma(x) = rcp(1 + exp2(-x*log2e)), tanh(g) = 2*sigma(2g)-1, with the
//      -log2e / -2log2e folded into weights. 67 -> ~43 instrs/step, no
//      clamps (|pre-act| <= ~8 so exp2 in [2^-12, 2^12]), EXACT sigmoid
//      (better accuracy than the Pade it replaces).
//  (2) RESIDUE: asymmetric s_setprio to break co-wave lockstep: the two
//      co-resident blocks on a CU ((bid>>8)&1 differ for 512 blocks over
//      256 CUs) get different priority -> anti-phase stalls instead of
//      correlated ones.
// ---------------------------------------------------------------------------
__global__ __launch_bounds__(256, 2) void lstm_kernel(const float* __restrict__ x,
                                                      const float* __restrict__ Wih,
                                                      const float* __restrict__ Whh,
                                                      const float* __restrict__ bih,
                                                      const float* __restrict__ bhh,
                                                      const int* __restrict__ lengths,
                                                      const int* __restrict__ perm,
                                                      float* __restrict__ out) {
    const int gtid = blockIdx.x * 256 + threadIdx.x;
    const int grp  = gtid >> 3;              // group-of-8 index = sorted rank
    const int lsub = threadIdx.x & 7;
    const int k    = min(lsub, 4);           // owned hidden index

    // Symmetry-break: half the blocks run at wave priority 1 so co-resident
    // waves on a SIMD stall anti-phase instead of in lockstep.
    if ((blockIdx.x >> 8) & 1) __builtin_amdgcn_s_setprio(1);

    const int b   = perm[grp];
    const int len = lengths[b];

    // Gate rows: i=k, f=5+k, g=10+k, o=15+k. Pairs A=(i,f), B=(g,o).
    // Scale: i,f,o rows by -log2e (sigmoid via exp2), g row by -2*log2e
    // (tanh via 2*sigma(2g)-1). All folded into weights+bias.
    const float S1 = -1.4426950408889634f;   // -log2(e)
    const float S2 = 2.0f * S1;              // -2*log2(e)
    v2f wihA, wihB, bA, bB, whhA[HIDn], whhB[HIDn];
    {
        const int gi = k, gf = 5 + k, gg = 10 + k, go = 15 + k;
        wihA = (v2f){ Wih[gi] * S1, Wih[gf] * S1 };
        wihB = (v2f){ Wih[gg] * S2, Wih[go] * S1 };
        bA   = (v2f){ (bih[gi] + bhh[gi]) * S1, (bih[gf] + bhh[gf]) * S1 };
        bB   = (v2f){ (bih[gg] + bhh[gg]) * S2, (bih[go] + bhh[go]) * S1 };
        #pragma unroll
        for (int kk = 0; kk < HIDn; ++kk) {
            whhA[kk] = (v2f){ Whh[gi * HIDn + kk] * S1, Whh[gf * HIDn + kk] * S1 };
            whhB[kk] = (v2f){ Whh[gg * HIDn + kk] * S2, Whh[go * HIDn + kk] * S1 };
        }
    }

    const float* xrow = x + (size_t)b * Tn;
    float h0 = 0, h1 = 0, h2 = 0, h3 = 0, h4 = 0;
    float hq = 0, c = 0;

    float4 xq = *reinterpret_cast<const float4*>(xrow);
    for (int t = 0; __any(t < len); t += 4) {
        const float4 xn = *reinterpret_cast<const float4*>(xrow + min(t + 4, Tn - 4));
        const float xs[4] = { xq.x, xq.y, xq.z, xq.w };
        #pragma unroll
        for (int s = 0; s < 4; ++s) {
            const float xv = xs[s];
            // Packed pre-activations (6 pk_fma per pair), pre-scaled.
            v2f pA = xv * wihA + bA;
            v2f pB = xv * wihB + bB;
            pA = h0 * whhA[0] + pA;  pB = h0 * whhB[0] + pB;
            pA = h1 * whhA[1] + pA;  pB = h1 * whhB[1] + pB;
            pA = h2 * whhA[2] + pA;  pB = h2 * whhB[2] + pB;
            pA = h3 * whhA[3] + pA;  pB = h3 * whhB[3] + pB;
            pA = h4 * whhA[4] + pA;  pB = h4 * whhB[4] + pB;
            // Exact activations via hardware exp2 (pre-acts carry -log2e).
            const float eI = exp2_fast(pA.x);
            const float eF = exp2_fast(pA.y);
            const float eG = exp2_fast(pB.x);
            const float eO = exp2_fast(pB.y);
            const float gi_ = rcp_fast(1.0f + eI);   // sigmoid(i)
            const float gf_ = rcp_fast(1.0f + eF);   // sigmoid(f)
            const float rg  = rcp_fast(1.0f + eG);   // sigma(2g)
            const float oo  = rcp_fast(1.0f + eO);   // sigmoid(o)
            const float tg  = fmaf(2.0f, rg, -1.0f); // tanh(g)

            const float cn = fmaf(gf_, c, gi_ * tg);

            // Spine: tanh(cn) via sigma(2*cn); hn = oo*(2*rc - 1).
            const float ec  = exp2_fast(cn * S2);
            const float rc  = rcp_fast(1.0f + ec);
            const float oo2 = oo + oo;               // off-chain, overlaps exp
            const float hn  = fmaf(oo2, rc, -oo);

            // Conditional commit (cndmask); frozen past len.
            const bool upd = (t + s) < len;
            c  = upd ? cn : c;
            hq = upd ? hn : hq;

            h0 = bcast8<0>(hq);
            h1 = bcast8<1>(hq);
            h2 = bcast8<2>(hq);
            h3 = bcast8<3>(hq);
            h4 = bcast8<4>(hq);
        }
        xq = xn;
    }

    if (lsub < HIDn) out[(size_t)b * HIDn + lsub] = hq;
}

extern "C" void kernel_launch(void* const* d_in, const int* in_sizes, int n_in,
                              void* d_out, int out_size, void* d_ws, size_t ws_size,
                              hipStream_t stream) {
    const float* x   = (const float*)d_in[0];  // [B,1,T,1]
    const float* Wih = (const float*)d_in[1];  // [20,1]
    const float* Whh = (const float*)d_in[2];  // [20,5]
    const float* bih = (const float*)d_in[3];  // [20]
    const float* bhh = (const float*)d_in[4];  // [20]
    float* out = (float*)d_out;                // [1,B,5]

    int* lengths = (int*)d_ws;                 // [0, Bn)
    int* perm    = lengths + Bn;               // [Bn, 2Bn)
    int* gbins   = perm + Bn;                  // [2Bn, 2Bn+NBINS)

    zero_kernel<<<NBINS / 256, 256, 0, stream>>>(gbins);
    len_kernel<<<Bn / 4, 256, 0, stream>>>(x, lengths, gbins);
    sort_kernel<<<1, 1024, 0, stream>>>(lengths, gbins, perm);
    lstm_kernel<<<Bn * 8 / 256, 256, 0, stream>>>(x, Wih, Whh, bih, bhh,
                                                  lengths, perm, out);
}